// Round 9
// baseline (521.485 us; speedup 1.0000x reference)
//
#include <hip/hip_runtime.h>

#define VDIM 20000
#define EDIM 128
#define BATCH 64
#define SEQ 100
#define BN 96
#define NVT 209   // ceil(20000/96)

typedef float f32x4 __attribute__((ext_vector_type(4)));
typedef short bf16x8 __attribute__((ext_vector_type(8)));
typedef unsigned short ushortx8 __attribute__((ext_vector_type(8)));

typedef __attribute__((address_space(1))) const unsigned int gas_u32;
typedef __attribute__((address_space(3))) unsigned int las_u32;

__device__ __forceinline__ void async16(unsigned short* lds, const unsigned short* g) {
  __builtin_amdgcn_global_load_lds((gas_u32*)g, (las_u32*)lds, 16, 0, 0);
}

__device__ __forceinline__ unsigned short f2bf(float f) {
  unsigned u = __builtin_bit_cast(unsigned, f);
  u += 0x7FFFu + ((u >> 16) & 1u);   // RTNE
  return (unsigned short)(u >> 16);
}

// ---- fused prep: W->bf16 (blocks 0..2499) + A gather PRE-SWIZZLED (2500..2627)
__global__ void prep_kernel(const float* __restrict__ Wi, const float* __restrict__ Wu,
                            const int* __restrict__ attr_item, const int* __restrict__ attr_user,
                            const int* __restrict__ item_ids, const int* __restrict__ user_ids,
                            const float* __restrict__ item_emb, const float* __restrict__ user_emb,
                            unsigned short* __restrict__ wbf, unsigned short* __restrict__ abf) {
  const int bid = blockIdx.x, t = threadIdx.x;
  if (bid < 2500) {
    const int c = bid & 1;
    const float* src = c ? Wu : Wi;
    unsigned short* dst = wbf + (size_t)c * (VDIM * EDIM);
    const int i0 = ((bid >> 1) * 256 + t) * 8;
    float4 a = *(const float4*)(src + i0);
    float4 b = *(const float4*)(src + i0 + 4);
    ushortx8 o;
    o[0] = f2bf(a.x); o[1] = f2bf(a.y); o[2] = f2bf(a.z); o[3] = f2bf(a.w);
    o[4] = f2bf(b.x); o[5] = f2bf(b.y); o[6] = f2bf(b.z); o[7] = f2bf(b.w);
    *(ushortx8*)(dst + i0) = o;
  } else {
    const int g = bid - 2500;
    const int b = g & 63, c = g >> 6;
    const int r = t >> 1, h = t & 1;
    const int* ids = c ? attr_user : attr_item;
    const float* W = c ? Wu : Wi;
    const float* demb = c ? user_emb : item_emb;
    const int* dids = c ? user_ids : item_ids;
    unsigned short* dst = abf + (size_t)(c * BATCH + b) * 16384;
    const float* src = nullptr;
    if (r < SEQ)       src = W + (size_t)ids[b * SEQ + r] * EDIM;
    else if (r == SEQ) src = demb + (size_t)dids[b] * EDIM;
    if (src) {
      #pragma unroll
      for (int k = 0; k < 8; ++k) {
        const int jj = h * 8 + k;
        const int j = jj ^ (r & 15);
        float4 a  = *(const float4*)(src + j * 8);
        float4 bb = *(const float4*)(src + j * 8 + 4);
        ushortx8 o;
        o[0] = f2bf(a.x);  o[1] = f2bf(a.y);  o[2] = f2bf(a.z);  o[3] = f2bf(a.w);
        o[4] = f2bf(bb.x); o[5] = f2bf(bb.y); o[6] = f2bf(bb.z); o[7] = f2bf(bb.w);
        *(ushortx8*)(dst + (r * 16 + jj) * 8) = o;
      }
    } else {
      ushortx8 z = {0, 0, 0, 0, 0, 0, 0, 0};
      #pragma unroll
      for (int k = 0; k < 8; ++k) *(ushortx8*)(dst + (r * 16 + h * 8 + k) * 8) = z;
    }
  }
}

// ---- main: 256 thr (4 waves: wm2 x wn2), tile 128 rows x 96 cols (Mt4 x Nt3).
// breg 48 VGPR + acc 48 AGPR => total ~158 regs => 3 waves/SIMD under
// __launch_bounds__(256,3). Single-buffered DMA'd A tile (32KB, 2 barriers per
// stage, DMA latency covered by epilogue). LDS ~45KB => 3 blocks/CU.
__global__ __launch_bounds__(256, 3)
void main_kernel(const unsigned short* __restrict__ wbf, const unsigned short* __restrict__ abf,
                 const float* __restrict__ tf_item, const int* __restrict__ lens_item,
                 const float* __restrict__ tf_user, const int* __restrict__ lens_user,
                 float* __restrict__ out) {
  __shared__ __align__(16) unsigned short sA[16384];   // 32KB swizzled A tile
  __shared__ float sDen[2][2][BN];                     // [parity][wm][col]
  __shared__ float sNum[2][2][BN];
  __shared__ float sDir[2][BN];
  __shared__ float sTF[2][4][128];
  __shared__ int   sLen[2][4];
  __shared__ float sRes[4][BN];

  const int t = threadIdx.x;
  const int v0 = blockIdx.x * BN;          // 209 v-tiles
  const int bg4 = blockIdx.y * 4;          // 16 b-groups
  const int lane = t & 63, wave = t >> 6;
  const int wm = wave >> 1, wn = wave & 1;
  const int quad = lane >> 4, l15 = lane & 15;

  // ---- stage tf / lens into LDS (shift-only indexing) ----
  #pragma unroll
  for (int k = t; k < 1024; k += 256) {
    const int c = k >> 9, bi = (k >> 7) & 3, si = k & 127;
    float w = 0.f;
    if (si < SEQ) w = (c ? tf_user : tf_item)[(bg4 + bi) * SEQ + si];
    sTF[c][bi][si] = w;
  }
  if (t < 8) sLen[t >> 2][t & 3] = ((t >= 4) ? lens_user : lens_item)[bg4 + (t & 3)];

  // ---- B fragments for cluster 0 (48 VGPRs) ----
  bf16x8 breg[3][4];
  #pragma unroll
  for (int nt = 0; nt < 3; ++nt) {
    const int v = v0 + wn * 48 + nt * 16 + l15;
    const unsigned short* p = wbf + (size_t)v * EDIM + quad * 8;
    const bool ok = (v < VDIM);
    #pragma unroll
    for (int ks = 0; ks < 4; ++ks) {
      bf16x8 z = {0, 0, 0, 0, 0, 0, 0, 0};
      breg[nt][ks] = ok ? *(const bf16x8*)(p + ks * 32) : z;
    }
  }

  // ---- issue async A DMA for stage 0 ----
  {
    const unsigned short* gb = abf + (size_t)bg4 * 16384;
    #pragma unroll
    for (int i = 0; i < 8; ++i)
      async16(&sA[(i * 256 + wave * 64) * 8], gb + (size_t)(i * 256 + t) * 8);
  }

  #pragma unroll 1
  for (int s = 0; s < 8; ++s) {
    const int c = s >> 2, it = s & 3, buf = s & 1;

    __syncthreads();   // #1: DMA drained (sA = tile s); prev partials visible

    // ---- combine previous stage's partials (t<96 owns col t) ----
    if (s > 0 && t < BN) {
      const int ps = s - 1, p = ps & 1, pit = ps & 3;
      float den = sDen[p][0][t] + sDen[p][1][t];
      float num = sNum[p][0][t] + sNum[p][1][t];
      const float dir = sDir[p][t];
      den -= 11.f + __expf(dir);                 // 11 pad rows (101..111) + dir row
      const float val = num * __builtin_amdgcn_rcpf(den) + dir;
      if (ps < 4) sRes[pit][t] = val;
      else {
        const int v = v0 + t;
        if (v < VDIM) out[(size_t)(bg4 + pit) * VDIM + v] = sRes[pit][t] + val;
      }
    }

    // ---- GEMM: 4x3 tiles of 16x16x32; A from LDS (swizzled), B from regs ----
    f32x4 acc[4][3];
    #pragma unroll
    for (int mt = 0; mt < 4; ++mt)
      #pragma unroll
      for (int nt = 0; nt < 3; ++nt) { f32x4 z = {0.f, 0.f, 0.f, 0.f}; acc[mt][nt] = z; }

    const unsigned char* pA = (const unsigned char*)&sA[0];
    #pragma unroll
    for (int ks = 0; ks < 4; ++ks) {
      const int j = ks * 4 + quad;
      const int sw = ((j ^ l15) << 4);
      bf16x8 af[4];
      #pragma unroll
      for (int mt = 0; mt < 4; ++mt)
        af[mt] = *(const bf16x8*)(pA + (wm * 64 + mt * 16 + l15) * 256 + sw);
      #pragma unroll
      for (int mt = 0; mt < 4; ++mt)
        #pragma unroll
        for (int nt = 0; nt < 3; ++nt)
          acc[mt][nt] = __builtin_amdgcn_mfma_f32_16x16x32_bf16(af[mt], breg[nt][ks], acc[mt][nt], 0, 0, 0);
    }

    __syncthreads();   // #2: all waves done reading sA (+ combine done)

    // ---- issue next stage's A DMA (covered by epilogue below) ----
    if (s < 7) {
      const int ns = s + 1;
      const unsigned short* gb = abf + (size_t)((ns >> 2) * BATCH + bg4 + (ns & 3)) * 16384;
      #pragma unroll
      for (int i = 0; i < 8; ++i)
        async16(&sA[(i * 256 + wave * 64) * 8], gb + (size_t)(i * 256 + t) * 8);
    }
    // reload B for cluster 1 once
    if (s == 3) {
      const unsigned short* wb1 = wbf + (size_t)VDIM * EDIM;
      #pragma unroll
      for (int nt = 0; nt < 3; ++nt) {
        const int v = v0 + wn * 48 + nt * 16 + l15;
        const unsigned short* p = wb1 + (size_t)v * EDIM + quad * 8;
        const bool ok = (v < VDIM);
        #pragma unroll
        for (int ks = 0; ks < 4; ++ks) {
          bf16x8 z = {0, 0, 0, 0, 0, 0, 0, 0};
          breg[nt][ks] = ok ? *(const bf16x8*)(p + ks * 32) : z;
        }
      }
    }

    // ---- epilogue: softmax partials into parity slot ----
    // wm0: rows 0..63 (mt 0..3, all real). wm1: rows 64..127 -> mt 0..2 only
    // (rows 64..111; 101..111 are zero-pads contributing exp(0)=1, corrected
    // in combine); mt3 (rows 112..127, all pad) skipped entirely.
    const int lenb = sLen[c][it];
    const int mtend = (wm == 0) ? 4 : 3;
    float wv[4][4];
    #pragma unroll
    for (int mt = 0; mt < 4; ++mt)
      #pragma unroll
      for (int r = 0; r < 4; ++r) {
        const int row = wm * 64 + mt * 16 + quad * 4 + r;
        wv[mt][r] = (row < lenb) ? sTF[c][it][row & 127] : 0.f;
      }

    #pragma unroll
    for (int nt = 0; nt < 3; ++nt) {
      float den = 0.f, num = 0.f;
      for (int mt = 0; mt < mtend; ++mt)
        #pragma unroll
        for (int r = 0; r < 4; ++r) {
          const float v = acc[mt][nt][r];
          const float e = __expf(v);
          den += e;
          num = fmaf(wv[mt][r], e * v, num);
        }
      den += __shfl_xor(den, 16, 64);
      den += __shfl_xor(den, 32, 64);
      num += __shfl_xor(num, 16, 64);
      num += __shfl_xor(num, 32, 64);
      const int col = wn * 48 + nt * 16 + l15;
      if (quad == 0) {
        sDen[buf][wm][col] = den;
        sNum[buf][wm][col] = num;
      }
      // row 100 = wm1, mt2, quad1, r0
      if (wm == 1 && quad == 1) sDir[buf][col] = acc[2][nt][0];
    }
  }

  __syncthreads();

  // ---- combine final stage (ps=7, parity 1, it=3) ----
  if (t < BN) {
    float den = sDen[1][0][t] + sDen[1][1][t];
    float num = sNum[1][0][t] + sNum[1][1][t];
    const float dir = sDir[1][t];
    den -= 11.f + __expf(dir);
    const float val = num * __builtin_amdgcn_rcpf(den) + dir;
    const int v = v0 + t;
    if (v < VDIM) out[(size_t)(bg4 + 3) * VDIM + v] = sRes[3][t] + val;
  }
}

extern "C" void kernel_launch(void* const* d_in, const int* in_sizes, int n_in,
                              void* d_out, int out_size, void* d_ws, size_t ws_size,
                              hipStream_t stream) {
  const int*   attr_item = (const int*)d_in[0];
  const float* tf_item   = (const float*)d_in[1];
  const int*   lens_item = (const int*)d_in[2];
  const int*   item_ids  = (const int*)d_in[3];
  const int*   attr_user = (const int*)d_in[4];
  const float* tf_user   = (const float*)d_in[5];
  const int*   lens_user = (const int*)d_in[6];
  const int*   user_ids  = (const int*)d_in[7];
  const float* W_item    = (const float*)d_in[8];
  const float* W_user    = (const float*)d_in[9];
  const float* user_emb  = (const float*)d_in[10];
  const float* item_emb  = (const float*)d_in[11];
  float* out = (float*)d_out;

  unsigned short* wbf = (unsigned short*)d_ws;                  // [2][V][E] bf16 (linear)
  unsigned short* abf = wbf + (size_t)2 * VDIM * EDIM;          // [2][64] swizzled 32KB tiles

  prep_kernel<<<dim3(2500 + 128), 256, 0, stream>>>(W_item, W_user, attr_item, attr_user,
                                                    item_ids, user_ids, item_emb, user_emb,
                                                    wbf, abf);
  main_kernel<<<dim3(NVT, 16), 256, 0, stream>>>(wbf, abf, tf_item, lens_item,
                                                 tf_user, lens_user, out);
}

// Round 10
// 240.869 us; speedup vs baseline: 2.1650x; 2.1650x over previous
//
#include <hip/hip_runtime.h>

#define VDIM 20000
#define EDIM 128
#define BATCH 64
#define SEQ 100
#define BN 96
#define NVT 209   // ceil(20000/96)

typedef float f32x4 __attribute__((ext_vector_type(4)));
typedef short bf16x8 __attribute__((ext_vector_type(8)));
typedef unsigned short ushortx8 __attribute__((ext_vector_type(8)));

typedef __attribute__((address_space(1))) const unsigned int gas_u32;
typedef __attribute__((address_space(3))) unsigned int las_u32;

__device__ __forceinline__ void async16(unsigned short* lds, const unsigned short* g) {
  __builtin_amdgcn_global_load_lds((gas_u32*)g, (las_u32*)lds, 16, 0, 0);
}

__device__ __forceinline__ unsigned short f2bf(float f) {
  unsigned u = __builtin_bit_cast(unsigned, f);
  u += 0x7FFFu + ((u >> 16) & 1u);   // RTNE
  return (unsigned short)(u >> 16);
}

// ---- fused prep: W->bf16 (blocks 0..2499) + A gather PRE-SWIZZLED (2500..2627)
__global__ void prep_kernel(const float* __restrict__ Wi, const float* __restrict__ Wu,
                            const int* __restrict__ attr_item, const int* __restrict__ attr_user,
                            const int* __restrict__ item_ids, const int* __restrict__ user_ids,
                            const float* __restrict__ item_emb, const float* __restrict__ user_emb,
                            unsigned short* __restrict__ wbf, unsigned short* __restrict__ abf) {
  const int bid = blockIdx.x, t = threadIdx.x;
  if (bid < 2500) {
    const int c = bid & 1;
    const float* src = c ? Wu : Wi;
    unsigned short* dst = wbf + (size_t)c * (VDIM * EDIM);
    const int i0 = ((bid >> 1) * 256 + t) * 8;
    float4 a = *(const float4*)(src + i0);
    float4 b = *(const float4*)(src + i0 + 4);
    ushortx8 o;
    o[0] = f2bf(a.x); o[1] = f2bf(a.y); o[2] = f2bf(a.z); o[3] = f2bf(a.w);
    o[4] = f2bf(b.x); o[5] = f2bf(b.y); o[6] = f2bf(b.z); o[7] = f2bf(b.w);
    *(ushortx8*)(dst + i0) = o;
  } else {
    const int g = bid - 2500;
    const int b = g & 63, c = g >> 6;
    const int r = t >> 1, h = t & 1;
    const int* ids = c ? attr_user : attr_item;
    const float* W = c ? Wu : Wi;
    const float* demb = c ? user_emb : item_emb;
    const int* dids = c ? user_ids : item_ids;
    unsigned short* dst = abf + (size_t)(c * BATCH + b) * 16384;
    const float* src = nullptr;
    if (r < SEQ)       src = W + (size_t)ids[b * SEQ + r] * EDIM;
    else if (r == SEQ) src = demb + (size_t)dids[b] * EDIM;
    if (src) {
      #pragma unroll
      for (int k = 0; k < 8; ++k) {
        const int jj = h * 8 + k;
        const int j = jj ^ (r & 15);
        float4 a  = *(const float4*)(src + j * 8);
        float4 bb = *(const float4*)(src + j * 8 + 4);
        ushortx8 o;
        o[0] = f2bf(a.x);  o[1] = f2bf(a.y);  o[2] = f2bf(a.z);  o[3] = f2bf(a.w);
        o[4] = f2bf(bb.x); o[5] = f2bf(bb.y); o[6] = f2bf(bb.z); o[7] = f2bf(bb.w);
        *(ushortx8*)(dst + (r * 16 + jj) * 8) = o;
      }
    } else {
      ushortx8 z = {0, 0, 0, 0, 0, 0, 0, 0};
      #pragma unroll
      for (int k = 0; k < 8; ++k) *(ushortx8*)(dst + (r * 16 + h * 8 + k) * 8) = z;
    }
  }
}

// ---- main: 256 thr (4 waves: wm2 x wn2), tile 128 rows x 96 cols (Mt4 x Nt3).
// breg 48 VGPR + acc 48 AGPR => ~160 total => 3 waves/SIMD under
// __launch_bounds__(256,3). Single-buffered DMA'd A tile; 2 barriers/stage.
// CRITICAL: all register arrays statically indexed (R9's runtime-bound mt loop
// demoted acc to scratch -> 1.26 GB of spill traffic).
__global__ __launch_bounds__(256, 3)
void main_kernel(const unsigned short* __restrict__ wbf, const unsigned short* __restrict__ abf,
                 const float* __restrict__ tf_item, const int* __restrict__ lens_item,
                 const float* __restrict__ tf_user, const int* __restrict__ lens_user,
                 float* __restrict__ out) {
  __shared__ __align__(16) unsigned short sA[16384];   // 32KB swizzled A tile
  __shared__ float sDen[2][2][BN];                     // [parity][wm][col]
  __shared__ float sNum[2][2][BN];
  __shared__ float sDir[2][BN];
  __shared__ float sTF[2][4][128];
  __shared__ int   sLen[2][4];
  __shared__ float sRes[4][BN];

  const int t = threadIdx.x;
  const int v0 = blockIdx.x * BN;          // 209 v-tiles
  const int bg4 = blockIdx.y * 4;          // 16 b-groups
  const int lane = t & 63, wave = t >> 6;
  const int wm = wave >> 1, wn = wave & 1;
  const int quad = lane >> 4, l15 = lane & 15;

  // ---- stage tf / lens into LDS (shift-only indexing) ----
  #pragma unroll
  for (int k = t; k < 1024; k += 256) {
    const int c = k >> 9, bi = (k >> 7) & 3, si = k & 127;
    float w = 0.f;
    if (si < SEQ) w = (c ? tf_user : tf_item)[(bg4 + bi) * SEQ + si];
    sTF[c][bi][si] = w;
  }
  if (t < 8) sLen[t >> 2][t & 3] = ((t >= 4) ? lens_user : lens_item)[bg4 + (t & 3)];

  // ---- B fragments for cluster 0 (48 VGPRs) ----
  bf16x8 breg[3][4];
  #pragma unroll
  for (int nt = 0; nt < 3; ++nt) {
    const int v = v0 + wn * 48 + nt * 16 + l15;
    const unsigned short* p = wbf + (size_t)v * EDIM + quad * 8;
    const bool ok = (v < VDIM);
    #pragma unroll
    for (int ks = 0; ks < 4; ++ks) {
      bf16x8 z = {0, 0, 0, 0, 0, 0, 0, 0};
      breg[nt][ks] = ok ? *(const bf16x8*)(p + ks * 32) : z;
    }
  }

  // ---- issue async A DMA for stage 0 ----
  {
    const unsigned short* gb = abf + (size_t)bg4 * 16384;
    #pragma unroll
    for (int i = 0; i < 8; ++i)
      async16(&sA[(i * 256 + wave * 64) * 8], gb + (size_t)(i * 256 + t) * 8);
  }

  #pragma unroll 1
  for (int s = 0; s < 8; ++s) {
    const int c = s >> 2, it = s & 3, buf = s & 1;

    __syncthreads();   // #1: DMA drained (sA = tile s); prev partials visible

    // ---- combine previous stage's partials (t<96 owns col t) ----
    if (s > 0 && t < BN) {
      const int ps = s - 1, p = ps & 1, pit = ps & 3;
      float den = sDen[p][0][t] + sDen[p][1][t];
      float num = sNum[p][0][t] + sNum[p][1][t];
      const float dir = sDir[p][t];
      den -= 11.f + __expf(dir);                 // 11 pad rows (101..111) + dir row
      const float val = num * __builtin_amdgcn_rcpf(den) + dir;
      if (ps < 4) sRes[pit][t] = val;
      else {
        const int v = v0 + t;
        if (v < VDIM) out[(size_t)(bg4 + pit) * VDIM + v] = sRes[pit][t] + val;
      }
    }

    // ---- GEMM: 4x3 tiles of 16x16x32; A from LDS (swizzled), B from regs ----
    f32x4 acc[4][3];
    #pragma unroll
    for (int mt = 0; mt < 4; ++mt)
      #pragma unroll
      for (int nt = 0; nt < 3; ++nt) { f32x4 z = {0.f, 0.f, 0.f, 0.f}; acc[mt][nt] = z; }

    const unsigned char* pA = (const unsigned char*)&sA[0];
    #pragma unroll
    for (int ks = 0; ks < 4; ++ks) {
      const int j = ks * 4 + quad;
      const int sw = ((j ^ l15) << 4);
      bf16x8 af[4];
      #pragma unroll
      for (int mt = 0; mt < 4; ++mt)
        af[mt] = *(const bf16x8*)(pA + (wm * 64 + mt * 16 + l15) * 256 + sw);
      #pragma unroll
      for (int mt = 0; mt < 4; ++mt)
        #pragma unroll
        for (int nt = 0; nt < 3; ++nt)
          acc[mt][nt] = __builtin_amdgcn_mfma_f32_16x16x32_bf16(af[mt], breg[nt][ks], acc[mt][nt], 0, 0, 0);
    }

    __syncthreads();   // #2: all waves done reading sA (+ combine done)

    // ---- issue next stage's A DMA (covered by epilogue below) ----
    if (s < 7) {
      const int ns = s + 1;
      const unsigned short* gb = abf + (size_t)((ns >> 2) * BATCH + bg4 + (ns & 3)) * 16384;
      #pragma unroll
      for (int i = 0; i < 8; ++i)
        async16(&sA[(i * 256 + wave * 64) * 8], gb + (size_t)(i * 256 + t) * 8);
    }
    // reload B for cluster 1 once
    if (s == 3) {
      const unsigned short* wb1 = wbf + (size_t)VDIM * EDIM;
      #pragma unroll
      for (int nt = 0; nt < 3; ++nt) {
        const int v = v0 + wn * 48 + nt * 16 + l15;
        const unsigned short* p = wb1 + (size_t)v * EDIM + quad * 8;
        const bool ok = (v < VDIM);
        #pragma unroll
        for (int ks = 0; ks < 4; ++ks) {
          bf16x8 z = {0, 0, 0, 0, 0, 0, 0, 0};
          breg[nt][ks] = ok ? *(const bf16x8*)(p + ks * 32) : z;
        }
      }
    }

    // ---- epilogue: softmax partials into parity slot (ALL static indexing) --
    // wm0: rows 0..63 (mt 0..3 real). wm1: mt 0..2 = rows 64..111 (101..111
    // zero-pads -> exp(0)=1, corrected in combine); mt3 (112..127) skipped via
    // wave-uniform branch with STATIC acc[3][nt] indexing.
    const int lenb = sLen[c][it];
    float wv[4][4];
    #pragma unroll
    for (int mt = 0; mt < 4; ++mt)
      #pragma unroll
      for (int r = 0; r < 4; ++r) {
        const int row = wm * 64 + mt * 16 + quad * 4 + r;
        wv[mt][r] = (row < lenb) ? sTF[c][it][row & 127] : 0.f;
      }

    #pragma unroll
    for (int nt = 0; nt < 3; ++nt) {
      float den = 0.f, num = 0.f;
      #pragma unroll
      for (int mt = 0; mt < 3; ++mt)
        #pragma unroll
        for (int r = 0; r < 4; ++r) {
          const float v = acc[mt][nt][r];
          const float e = __expf(v);
          den += e;
          num = fmaf(wv[mt][r], e * v, num);
        }
      if (wm == 0) {   // wave-uniform; static index acc[3][nt]
        #pragma unroll
        for (int r = 0; r < 4; ++r) {
          const float v = acc[3][nt][r];
          const float e = __expf(v);
          den += e;
          num = fmaf(wv[3][r], e * v, num);
        }
      }
      den += __shfl_xor(den, 16, 64);
      den += __shfl_xor(den, 32, 64);
      num += __shfl_xor(num, 16, 64);
      num += __shfl_xor(num, 32, 64);
      const int col = wn * 48 + nt * 16 + l15;
      if (quad == 0) {
        sDen[buf][wm][col] = den;
        sNum[buf][wm][col] = num;
      }
      // row 100 = wm1, mt2, quad1, r0
      if (wm == 1 && quad == 1) sDir[buf][col] = acc[2][nt][0];
    }
  }

  __syncthreads();

  // ---- combine final stage (ps=7, parity 1, it=3) ----
  if (t < BN) {
    float den = sDen[1][0][t] + sDen[1][1][t];
    float num = sNum[1][0][t] + sNum[1][1][t];
    const float dir = sDir[1][t];
    den -= 11.f + __expf(dir);
    const float val = num * __builtin_amdgcn_rcpf(den) + dir;
    const int v = v0 + t;
    if (v < VDIM) out[(size_t)(bg4 + 3) * VDIM + v] = sRes[3][t] + val;
  }
}

extern "C" void kernel_launch(void* const* d_in, const int* in_sizes, int n_in,
                              void* d_out, int out_size, void* d_ws, size_t ws_size,
                              hipStream_t stream) {
  const int*   attr_item = (const int*)d_in[0];
  const float* tf_item   = (const float*)d_in[1];
  const int*   lens_item = (const int*)d_in[2];
  const int*   item_ids  = (const int*)d_in[3];
  const int*   attr_user = (const int*)d_in[4];
  const float* tf_user   = (const float*)d_in[5];
  const int*   lens_user = (const int*)d_in[6];
  const int*   user_ids  = (const int*)d_in[7];
  const float* W_item    = (const float*)d_in[8];
  const float* W_user    = (const float*)d_in[9];
  const float* user_emb  = (const float*)d_in[10];
  const float* item_emb  = (const float*)d_in[11];
  float* out = (float*)d_out;

  unsigned short* wbf = (unsigned short*)d_ws;                  // [2][V][E] bf16 (linear)
  unsigned short* abf = wbf + (size_t)2 * VDIM * EDIM;          // [2][64] swizzled 32KB tiles

  prep_kernel<<<dim3(2500 + 128), 256, 0, stream>>>(W_item, W_user, attr_item, attr_user,
                                                    item_ids, user_ids, item_emb, user_emb,
                                                    wbf, abf);
  main_kernel<<<dim3(NVT, 16), 256, 0, stream>>>(wbf, abf, tf_item, lens_item,
                                                 tf_user, lens_user, out);
}